// Round 1
// baseline (353.225 us; speedup 1.0000x reference)
//
#include <hip/hip_runtime.h>
#include <cstdint>
#include <cstddef>

#define DEV __device__ __forceinline__

typedef __bf16 v8bf __attribute__((ext_vector_type(8)));
typedef float v4f __attribute__((ext_vector_type(4)));
typedef uint16_t u16;

DEV u16 f2bf(float f) {
    uint32_t u = __float_as_uint(f);
    u += 0x7FFF + ((u >> 16) & 1);   // RNE
    return (u16)(u >> 16);
}
DEV float bf2f(u16 h) { return __uint_as_float((uint32_t)h << 16); }

// ---------------- f32 -> bf16 convert (vectorized) ----------------
__global__ __launch_bounds__(256) void k_cvt(const float* __restrict__ src, u16* __restrict__ dst) {
    int i = blockIdx.x * 256 + threadIdx.x;
    float4 v = reinterpret_cast<const float4*>(src)[i];
    ushort4 o;
    o.x = f2bf(v.x); o.y = f2bf(v.y); o.z = f2bf(v.z); o.w = f2bf(v.w);
    reinterpret_cast<ushort4*>(dst)[i] = o;
}

// ---------------- weight transpose + convert: Wt[n][k] = bf16(W[k][n]) ----------------
__global__ __launch_bounds__(256) void k_transpose_w(
    const float* __restrict__ w0, const float* __restrict__ w1, const float* __restrict__ w2,
    const float* __restrict__ w3, const float* __restrict__ w4, const float* __restrict__ w5,
    const float* __restrict__ w6, u16* __restrict__ Wt) {
    __shared__ float tl[32][33];
    const float* W;
    switch (blockIdx.z) {
        case 0: W = w0; break; case 1: W = w1; break; case 2: W = w2; break;
        case 3: W = w3; break; case 4: W = w4; break; case 5: W = w5; break;
        default: W = w6; break;
    }
    int n0 = blockIdx.x * 32, k0 = blockIdx.y * 32;
    int tx = threadIdx.x & 31, ty = threadIdx.x >> 5;
    #pragma unroll
    for (int i = 0; i < 4; ++i)
        tl[ty + i*8][tx] = W[(size_t)(k0 + ty + i*8) * 768 + n0 + tx];
    __syncthreads();
    u16* O = Wt + (size_t)blockIdx.z * 589824;
    #pragma unroll
    for (int i = 0; i < 4; ++i)
        O[(size_t)(n0 + ty + i*8) * 768 + k0 + tx] = f2bf(tl[tx][ty + i*8]);
}

// ---------------- bf16 MFMA GEMM core: C[128x128] = A[M,768] * Wt[N,768]^T ----------------
// LDS tiles [row][64] bf16, XOR-swizzled: byte ^= (row&7)<<4 (bank-conflict-free b128 reads).
DEV void gemm_main(const u16* __restrict__ A, const u16* __restrict__ W,
                   u16* As, u16* Bs, int m0, int n0, v4f acc[4][4]) {
    const int t = threadIdx.x, lane = t & 63;
    const int wid = t >> 6, wm = wid >> 1, wn = wid & 1;
    const int lr = lane & 15, kg = lane >> 4;
    #pragma unroll
    for (int mi = 0; mi < 4; ++mi)
        #pragma unroll
        for (int ni = 0; ni < 4; ++ni) acc[mi][ni] = (v4f){0.f, 0.f, 0.f, 0.f};
    const int srow = t >> 3, sslot = t & 7;
    for (int kt = 0; kt < 12; ++kt) {
        int k0 = kt * 64;
        uint4 ga[4], gb[4];
        #pragma unroll
        for (int i = 0; i < 4; ++i) {
            int r = srow + i * 32;
            ga[i] = *reinterpret_cast<const uint4*>(A + (size_t)(m0 + r) * 768 + k0 + sslot * 8);
            gb[i] = *reinterpret_cast<const uint4*>(W + (size_t)(n0 + r) * 768 + k0 + sslot * 8);
        }
        __syncthreads();
        #pragma unroll
        for (int i = 0; i < 4; ++i) {
            int r = srow + i * 32;
            int boff = r * 128 + ((sslot ^ (r & 7)) << 4);
            *reinterpret_cast<uint4*>(reinterpret_cast<char*>(As) + boff) = ga[i];
            *reinterpret_cast<uint4*>(reinterpret_cast<char*>(Bs) + boff) = gb[i];
        }
        __syncthreads();
        #pragma unroll
        for (int kk = 0; kk < 2; ++kk) {
            int kb2 = (kk * 32 + kg * 8) * 2;
            v8bf af[4], bfr[4];
            #pragma unroll
            for (int mi = 0; mi < 4; ++mi) {
                int rr = wm * 64 + mi * 16 + lr;
                af[mi] = *reinterpret_cast<const v8bf*>(reinterpret_cast<const char*>(As) + rr * 128 + (kb2 ^ ((rr & 7) << 4)));
            }
            #pragma unroll
            for (int ni = 0; ni < 4; ++ni) {
                int rr = wn * 64 + ni * 16 + lr;
                bfr[ni] = *reinterpret_cast<const v8bf*>(reinterpret_cast<const char*>(Bs) + rr * 128 + (kb2 ^ ((rr & 7) << 4)));
            }
            #pragma unroll
            for (int mi = 0; mi < 4; ++mi)
                #pragma unroll
                for (int ni = 0; ni < 4; ++ni)
                    acc[mi][ni] = __builtin_amdgcn_mfma_f32_16x16x32_bf16(af[mi], bfr[ni], acc[mi][ni], 0, 0, 0);
        }
    }
}

// 5 projections in one launch: z = {qc,kc,vc | qs,vs}
__global__ __launch_bounds__(256) void k_gemm_proj(
    const u16* __restrict__ fcb, const u16* __restrict__ fsb, const u16* __restrict__ Wt,
    u16* __restrict__ qc, u16* __restrict__ kc, u16* __restrict__ vc,
    u16* __restrict__ qs, u16* __restrict__ vs) {
    __shared__ __align__(16) u16 As[8192], Bs[8192];
    const u16* A; const u16* W; u16* O;
    switch (blockIdx.z) {
        case 0:  A = fcb; W = Wt;              O = qc; break;
        case 1:  A = fcb; W = Wt + 589824;     O = kc; break;
        case 2:  A = fcb; W = Wt + 2 * 589824; O = vc; break;
        case 3:  A = fsb; W = Wt + 3 * 589824; O = qs; break;
        default: A = fsb; W = Wt + 4 * 589824; O = vs; break;
    }
    int m0 = blockIdx.y * 128, n0 = blockIdx.x * 128;
    v4f acc[4][4];
    gemm_main(A, W, As, Bs, m0, n0, acc);
    const int lane = threadIdx.x & 63, wid = threadIdx.x >> 6;
    const int wm = wid >> 1, wn = wid & 1, lr = lane & 15, kg = lane >> 4;
    #pragma unroll
    for (int mi = 0; mi < 4; ++mi)
        #pragma unroll
        for (int ni = 0; ni < 4; ++ni)
            #pragma unroll
            for (int r = 0; r < 4; ++r) {
                int rowg = m0 + wm * 64 + mi * 16 + kg * 4 + r;
                int colg = n0 + wn * 64 + ni * 16 + lr;
                O[(size_t)rowg * 768 + colg] = f2bf(acc[mi][ni][r]);
            }
}

// final 2 projections + bias -> f32 d_out
__global__ __launch_bounds__(256) void k_gemm_out(
    const u16* __restrict__ ocb, const u16* __restrict__ osb, const u16* __restrict__ Wt,
    const float* __restrict__ bpc, const float* __restrict__ bps, float* __restrict__ out) {
    __shared__ __align__(16) u16 As[8192], Bs[8192];
    const u16* A; const u16* W; const float* bias; float* O;
    if (blockIdx.z == 0) { A = ocb; W = Wt + 5 * 589824; bias = bpc; O = out; }
    else                 { A = osb; W = Wt + 6 * 589824; bias = bps; O = out + 3145728; }
    int m0 = blockIdx.y * 128, n0 = blockIdx.x * 128;
    v4f acc[4][4];
    gemm_main(A, W, As, Bs, m0, n0, acc);
    const int lane = threadIdx.x & 63, wid = threadIdx.x >> 6;
    const int wm = wid >> 1, wn = wid & 1, lr = lane & 15, kg = lane >> 4;
    #pragma unroll
    for (int mi = 0; mi < 4; ++mi)
        #pragma unroll
        for (int ni = 0; ni < 4; ++ni)
            #pragma unroll
            for (int r = 0; r < 4; ++r) {
                int rowg = m0 + wm * 64 + mi * 16 + kg * 4 + r;
                int colg = n0 + wn * 64 + ni * 16 + lr;
                O[(size_t)rowg * 768 + colg] = acc[mi][ni][r] + bias[colg];
            }
}

// ---------------- per-head-chunk L2 normalize of qs (in place) ----------------
__global__ __launch_bounds__(256) void k_norm_qs(u16* __restrict__ qs) {
    int row = blockIdx.x;
    int w = threadIdx.x >> 6, lane = threadIdx.x & 63;
    #pragma unroll
    for (int c = w; c < 12; c += 4) {
        size_t idx = (size_t)row * 768 + c * 64 + lane;
        float v = bf2f(qs[idx]);
        float ss = v * v;
        ss += __shfl_xor(ss, 1);  ss += __shfl_xor(ss, 2);  ss += __shfl_xor(ss, 4);
        ss += __shfl_xor(ss, 8);  ss += __shfl_xor(ss, 16); ss += __shfl_xor(ss, 32);
        qs[idx] = f2bf(v * rsqrtf(ss));
    }
}

// ---------------- V transpose: vT[(bh*64+d)*1024 + n] = v[(b*1024+n)*768 + h*64 + d] ----------------
__global__ __launch_bounds__(256) void k_transpose_v(
    const u16* __restrict__ vc, const u16* __restrict__ vs,
    u16* __restrict__ vcT, u16* __restrict__ vsT) {
    __shared__ u16 tile[64][65];
    const u16* src = blockIdx.z ? vs : vc;
    u16* dst = blockIdx.z ? vsT : vcT;
    int bh = blockIdx.y, b = bh / 12, h = bh % 12;
    int n0 = blockIdx.x * 64;
    int t = threadIdx.x;
    #pragma unroll
    for (int i = 0; i < 16; ++i) {
        int idx = i * 256 + t, n = idx >> 6, d = idx & 63;
        tile[n][d] = src[(size_t)(b * 1024 + n0 + n) * 768 + h * 64 + d];
    }
    __syncthreads();
    #pragma unroll
    for (int i = 0; i < 16; ++i) {
        int idx = i * 256 + t, d = idx >> 6, n = idx & 63;
        dst[(size_t)(bh * 64 + d) * 1024 + n0 + n] = tile[n][d];
    }
}

// ---------------- flash attention: S = 0.125*QcKc^T + gamma*Qsn Qsn^T; A=softmax(S); oc=A@Vc, os=A@Vs ----------------
__global__ __launch_bounds__(256) void k_attn(
    const u16* __restrict__ qc, const u16* __restrict__ kc, const u16* __restrict__ qsn,
    const u16* __restrict__ vcT, const u16* __restrict__ vsT,
    const float* __restrict__ gamma,
    u16* __restrict__ oc, u16* __restrict__ os) {
    __shared__ __align__(16) u16 K_s[4096], Q2_s[4096], Vc_s[4096], Vs_s[4096], P_s[4096];
    const int t = threadIdx.x, lane = t & 63, w = t >> 6;
    const int lr = lane & 15, kg = lane >> 4;
    const int qb = blockIdx.x, bh = blockIdx.y, b = bh / 12, h = bh % 12;
    const float gam = gamma[h];
    const float L2E = 1.44269504088896340736f;
    const float SC = 0.125f;

    // per-wave 16 q-rows: Q fragments held in registers for the whole KV sweep
    int qrow = qb * 64 + w * 16 + lr;
    const u16* q1p = qc  + (size_t)(b * 1024 + qrow) * 768 + h * 64 + kg * 8;
    const u16* q2p = qsn + (size_t)(b * 1024 + qrow) * 768 + h * 64 + kg * 8;
    v8bf qcA[2], qsA[2];
    qcA[0] = *reinterpret_cast<const v8bf*>(q1p);
    qcA[1] = *reinterpret_cast<const v8bf*>(q1p + 32);
    qsA[0] = *reinterpret_cast<const v8bf*>(q2p);
    qsA[1] = *reinterpret_cast<const v8bf*>(q2p + 32);

    v4f oAcc[4], sAcc[4];
    #pragma unroll
    for (int i = 0; i < 4; ++i) { oAcc[i] = (v4f){0.f,0.f,0.f,0.f}; sAcc[i] = (v4f){0.f,0.f,0.f,0.f}; }
    float m_i[4] = {-1.0e30f, -1.0e30f, -1.0e30f, -1.0e30f};
    float l_i[4] = {0.f, 0.f, 0.f, 0.f};

    const int srow = t >> 3, sslot = t & 7;
    for (int tile = 0; tile < 16; ++tile) {
        int kv0 = tile * 64;
        uint4 g0[2], g1[2], g2[2], g3[2];
        #pragma unroll
        for (int i = 0; i < 2; ++i) {
            int r = srow + i * 32;
            size_t kvg = (size_t)(b * 1024 + kv0 + r) * 768 + h * 64 + sslot * 8;
            g0[i] = *reinterpret_cast<const uint4*>(kc + kvg);
            g1[i] = *reinterpret_cast<const uint4*>(qsn + kvg);
            size_t vg = (size_t)(bh * 64 + r) * 1024 + kv0 + sslot * 8;
            g2[i] = *reinterpret_cast<const uint4*>(vcT + vg);
            g3[i] = *reinterpret_cast<const uint4*>(vsT + vg);
        }
        __syncthreads();   // previous tile's compute done
        #pragma unroll
        for (int i = 0; i < 2; ++i) {
            int r = srow + i * 32;
            int boff = r * 128 + ((sslot ^ (r & 7)) << 4);
            *reinterpret_cast<uint4*>(reinterpret_cast<char*>(K_s) + boff) = g0[i];
            *reinterpret_cast<uint4*>(reinterpret_cast<char*>(Q2_s) + boff) = g1[i];
            *reinterpret_cast<uint4*>(reinterpret_cast<char*>(Vc_s) + boff) = g2[i];
            *reinterpret_cast<uint4*>(reinterpret_cast<char*>(Vs_s) + boff) = g3[i];
        }
        __syncthreads();

        // S tile [16 q][64 kv]
        v4f sc[4], ss_[4];
        #pragma unroll
        for (int cb = 0; cb < 4; ++cb) {
            int kr = cb * 16 + lr;
            v4f ac = {0.f,0.f,0.f,0.f}, as = {0.f,0.f,0.f,0.f};
            #pragma unroll
            for (int kk = 0; kk < 2; ++kk) {
                int kb2 = (kk * 32 + kg * 8) * 2;
                int off = kr * 128 + (kb2 ^ ((kr & 7) << 4));
                v8bf kf  = *reinterpret_cast<const v8bf*>(reinterpret_cast<const char*>(K_s) + off);
                v8bf q2f = *reinterpret_cast<const v8bf*>(reinterpret_cast<const char*>(Q2_s) + off);
                ac = __builtin_amdgcn_mfma_f32_16x16x32_bf16(qcA[kk], kf,  ac, 0, 0, 0);
                as = __builtin_amdgcn_mfma_f32_16x16x32_bf16(qsA[kk], q2f, as, 0, 0, 0);
            }
            sc[cb] = ac; ss_[cb] = as;
        }
        // online softmax (rows owned by 16-lane groups; row = kg*4 + r)
        float pv[4][4];
        #pragma unroll
        for (int r = 0; r < 4; ++r) {
            float s0 = SC * sc[0][r] + gam * ss_[0][r];
            float s1 = SC * sc[1][r] + gam * ss_[1][r];
            float s2 = SC * sc[2][r] + gam * ss_[2][r];
            float s3 = SC * sc[3][r] + gam * ss_[3][r];
            float mx = fmaxf(fmaxf(s0, s1), fmaxf(s2, s3));
            mx = fmaxf(mx, __shfl_xor(mx, 1));
            mx = fmaxf(mx, __shfl_xor(mx, 2));
            mx = fmaxf(mx, __shfl_xor(mx, 4));
            mx = fmaxf(mx, __shfl_xor(mx, 8));
            float mn = fmaxf(m_i[r], mx);
            float fac = __builtin_exp2f((m_i[r] - mn) * L2E);
            m_i[r] = mn;
            float p0 = __builtin_exp2f((s0 - mn) * L2E);
            float p1 = __builtin_exp2f((s1 - mn) * L2E);
            float p2 = __builtin_exp2f((s2 - mn) * L2E);
            float p3 = __builtin_exp2f((s3 - mn) * L2E);
            pv[0][r] = p0; pv[1][r] = p1; pv[2][r] = p2; pv[3][r] = p3;
            float rs = p0 + p1 + p2 + p3;
            rs += __shfl_xor(rs, 1); rs += __shfl_xor(rs, 2);
            rs += __shfl_xor(rs, 4); rs += __shfl_xor(rs, 8);
            l_i[r] = l_i[r] * fac + rs;
            #pragma unroll
            for (int db = 0; db < 4; ++db) { oAcc[db][r] *= fac; sAcc[db][r] *= fac; }
        }
        // P -> per-wave LDS (C-frag -> A-frag layout transpose)
        #pragma unroll
        for (int cb = 0; cb < 4; ++cb)
            #pragma unroll
            for (int r = 0; r < 4; ++r) {
                int prow = kg * 4 + r, pcol = cb * 16 + lr;
                int off = w * 2048 + prow * 128 + ((pcol * 2) ^ ((prow & 7) << 4));
                *reinterpret_cast<u16*>(reinterpret_cast<char*>(P_s) + off) = f2bf(pv[cb][r]);
            }
        // PV: O[16 q][64 d] += P[16][64] @ V[64][64]
        #pragma unroll
        for (int kk = 0; kk < 2; ++kk) {
            int kb2 = (kk * 32 + kg * 8) * 2;
            int poff = w * 2048 + lr * 128 + (kb2 ^ ((lr & 7) << 4));
            v8bf ap = *reinterpret_cast<const v8bf*>(reinterpret_cast<const char*>(P_s) + poff);
            #pragma unroll
            for (int db = 0; db < 4; ++db) {
                int vr = db * 16 + lr;
                int voff = vr * 128 + (kb2 ^ ((vr & 7) << 4));
                v8bf vcf = *reinterpret_cast<const v8bf*>(reinterpret_cast<const char*>(Vc_s) + voff);
                v8bf vsf = *reinterpret_cast<const v8bf*>(reinterpret_cast<const char*>(Vs_s) + voff);
                oAcc[db] = __builtin_amdgcn_mfma_f32_16x16x32_bf16(ap, vcf, oAcc[db], 0, 0, 0);
                sAcc[db] = __builtin_amdgcn_mfma_f32_16x16x32_bf16(ap, vsf, sAcc[db], 0, 0, 0);
            }
        }
    }
    // epilogue: divide by l, store bf16
    #pragma unroll
    for (int r = 0; r < 4; ++r) {
        float rl = 1.0f / l_i[r];
        int qg = qb * 64 + w * 16 + kg * 4 + r;
        size_t base = (size_t)(b * 1024 + qg) * 768 + h * 64;
        #pragma unroll
        for (int db = 0; db < 4; ++db) {
            oc[base + db * 16 + lr] = f2bf(oAcc[db][r] * rl);
            os[base + db * 16 + lr] = f2bf(sAcc[db][r] * rl);
        }
    }
}

extern "C" void kernel_launch(void* const* d_in, const int* in_sizes, int n_in,
                              void* d_out, int out_size, void* d_ws, size_t ws_size,
                              hipStream_t stream) {
    const float* fc    = (const float*)d_in[0];
    const float* fs    = (const float*)d_in[1];
    const float* Wqc   = (const float*)d_in[2];
    const float* Wqs   = (const float*)d_in[3];
    const float* Wkc   = (const float*)d_in[4];
    const float* Wvc   = (const float*)d_in[5];
    const float* Wvs   = (const float*)d_in[6];
    const float* gamma = (const float*)d_in[7];
    const float* Wpc   = (const float*)d_in[8];
    const float* bpc   = (const float*)d_in[9];
    const float* Wps   = (const float*)d_in[10];
    const float* bps   = (const float*)d_in[11];
    float* out = (float*)d_out;

    const size_t NT = 3145728;  // 4096*768 elements
    u16* ws  = (u16*)d_ws;
    u16* fcb = ws;
    u16* fsb = fcb + NT;
    u16* Wt  = fsb + NT;            // 7 * 589824
    u16* qc  = Wt + (size_t)7 * 589824;
    u16* kc  = qc + NT;
    u16* vc  = kc + NT;
    u16* qs  = vc + NT;
    u16* vs  = qs + NT;
    u16* vcT = vs + NT;
    u16* vsT = vcT + NT;
    u16* ocb = fcb;  // fcb/fsb dead after projections -> reuse for attention outputs
    u16* osb = fsb;

    k_cvt<<<3072, 256, 0, stream>>>(fc, fcb);
    k_cvt<<<3072, 256, 0, stream>>>(fs, fsb);
    k_transpose_w<<<dim3(24, 24, 7), 256, 0, stream>>>(Wqc, Wkc, Wvc, Wqs, Wvs, Wpc, Wps, Wt);
    k_gemm_proj<<<dim3(6, 32, 5), 256, 0, stream>>>(fcb, fsb, Wt, qc, kc, vc, qs, vs);
    k_norm_qs<<<4096, 256, 0, stream>>>(qs);
    k_transpose_v<<<dim3(16, 48, 2), 256, 0, stream>>>(vc, vs, vcT, vsT);
    k_attn<<<dim3(16, 48), 256, 0, stream>>>(qc, kc, qs, vcT, vsT, gamma, ocb, osb);
    k_gemm_out<<<dim3(6, 32, 2), 256, 0, stream>>>(ocb, osb, Wt, bpc, bps, out);
}

// Round 2
// 187.220 us; speedup vs baseline: 1.8867x; 1.8867x over previous
//
#include <hip/hip_runtime.h>
#include <cstdint>
#include <cstddef>

#define DEV __device__ __forceinline__

typedef __bf16 v8bf __attribute__((ext_vector_type(8)));
typedef float v4f __attribute__((ext_vector_type(4)));
typedef uint16_t u16;

DEV u16 f2bf(float f) {
    union { __bf16 b; u16 u; } cv;
    cv.b = (__bf16)f;   // hardware RNE convert
    return cv.u;
}
DEV float bf2f(u16 h) { return __uint_as_float((uint32_t)h << 16); }

// async global -> LDS, 16B per lane; LDS dst is wave-uniform base + lane*16
DEV void gload16(void* lds, const void* g) {
    __builtin_amdgcn_global_load_lds(
        (const __attribute__((address_space(1))) unsigned int*)g,
        (__attribute__((address_space(3))) unsigned int*)lds, 16, 0, 0);
}

// ---------------- f32 -> bf16 convert of fc and fs (one launch) ----------------
__global__ __launch_bounds__(256) void k_cvt2(const float* __restrict__ a, const float* __restrict__ b,
                                              u16* __restrict__ da, u16* __restrict__ db) {
    const float* s = blockIdx.y ? b : a;
    u16* d = blockIdx.y ? db : da;
    int i = blockIdx.x * 256 + threadIdx.x;
    float4 v = reinterpret_cast<const float4*>(s)[i];
    ushort4 o;
    o.x = f2bf(v.x); o.y = f2bf(v.y); o.z = f2bf(v.z); o.w = f2bf(v.w);
    reinterpret_cast<ushort4*>(d)[i] = o;
}

// ---------------- weight transpose + convert: Wt[n][k] = bf16(W[k][n]) ----------------
__global__ __launch_bounds__(256) void k_transpose_w(
    const float* __restrict__ w0, const float* __restrict__ w1, const float* __restrict__ w2,
    const float* __restrict__ w3, const float* __restrict__ w4, const float* __restrict__ w5,
    const float* __restrict__ w6, u16* __restrict__ Wt) {
    __shared__ float tl[32][33];
    const float* W;
    switch (blockIdx.z) {
        case 0: W = w0; break; case 1: W = w1; break; case 2: W = w2; break;
        case 3: W = w3; break; case 4: W = w4; break; case 5: W = w5; break;
        default: W = w6; break;
    }
    int n0 = blockIdx.x * 32, k0 = blockIdx.y * 32;
    int tx = threadIdx.x & 31, ty = threadIdx.x >> 5;
    #pragma unroll
    for (int i = 0; i < 4; ++i)
        tl[ty + i*8][tx] = W[(size_t)(k0 + ty + i*8) * 768 + n0 + tx];
    __syncthreads();
    u16* O = Wt + (size_t)blockIdx.z * 589824;
    #pragma unroll
    for (int i = 0; i < 4; ++i)
        O[(size_t)(n0 + ty + i*8) * 768 + k0 + tx] = f2bf(tl[tx][ty + i*8]);
}

// ---------------- bf16 MFMA GEMM core: C[128x128] = A[M,768] * Wt[N,768]^T ----------------
// Staging via global_load_lds(16B): LDS linear in lane order, source pre-swizzled
// (slot s = (lane&7) ^ (lane>>3)) so the LDS image matches the XOR-swizzled read side.
DEV void gemm_main(const u16* __restrict__ A, const u16* __restrict__ W,
                   u16* As, u16* Bs, int m0, int n0, v4f acc[4][4]) {
    const int t = threadIdx.x, lane = t & 63;
    const int wid = t >> 6, wm = wid >> 1, wn = wid & 1;
    const int lr = lane & 15, kg = lane >> 4;
    const int lrow = lane >> 3, lslot = lane & 7;
    const int s = lslot ^ lrow;          // pre-swizzled source slot (row%8 == lrow)
    #pragma unroll
    for (int mi = 0; mi < 4; ++mi)
        #pragma unroll
        for (int ni = 0; ni < 4; ++ni) acc[mi][ni] = (v4f){0.f, 0.f, 0.f, 0.f};
    for (int kt = 0; kt < 12; ++kt) {
        int k0 = kt * 64;
        #pragma unroll
        for (int c = 0; c < 4; ++c) {
            int rb = wid * 32 + c * 8;
            int r = rb + lrow;
            gload16((char*)As + rb * 128, A + (size_t)(m0 + r) * 768 + k0 + s * 8);
            gload16((char*)Bs + rb * 128, W + (size_t)(n0 + r) * 768 + k0 + s * 8);
        }
        __syncthreads();
        #pragma unroll
        for (int kk = 0; kk < 2; ++kk) {
            int kb2 = (kk * 32 + kg * 8) * 2;
            v8bf af[4], bfr[4];
            #pragma unroll
            for (int mi = 0; mi < 4; ++mi) {
                int rr = wm * 64 + mi * 16 + lr;
                af[mi] = *reinterpret_cast<const v8bf*>(reinterpret_cast<const char*>(As) + rr * 128 + (kb2 ^ ((rr & 7) << 4)));
            }
            #pragma unroll
            for (int ni = 0; ni < 4; ++ni) {
                int rr = wn * 64 + ni * 16 + lr;
                bfr[ni] = *reinterpret_cast<const v8bf*>(reinterpret_cast<const char*>(Bs) + rr * 128 + (kb2 ^ ((rr & 7) << 4)));
            }
            #pragma unroll
            for (int mi = 0; mi < 4; ++mi)
                #pragma unroll
                for (int ni = 0; ni < 4; ++ni)
                    acc[mi][ni] = __builtin_amdgcn_mfma_f32_16x16x32_bf16(af[mi], bfr[ni], acc[mi][ni], 0, 0, 0);
        }
        __syncthreads();
    }
}

// 5 projections in one launch: z = {qc(*SCALE), kc, vc, qs(L2-normalized), vs}
__global__ __launch_bounds__(256) void k_gemm_proj(
    const u16* __restrict__ fcb, const u16* __restrict__ fsb, const u16* __restrict__ Wt,
    u16* __restrict__ qc, u16* __restrict__ kc, u16* __restrict__ vc,
    u16* __restrict__ qs, u16* __restrict__ vs) {
    __shared__ __align__(16) u16 As[8192], Bs[8192];
    const u16* A; const u16* W; u16* O;
    switch (blockIdx.z) {
        case 0:  A = fcb; W = Wt;              O = qc; break;
        case 1:  A = fcb; W = Wt + 589824;     O = kc; break;
        case 2:  A = fcb; W = Wt + 2 * 589824; O = vc; break;
        case 3:  A = fsb; W = Wt + 3 * 589824; O = qs; break;
        default: A = fsb; W = Wt + 4 * 589824; O = vs; break;
    }
    int m0 = blockIdx.y * 128, n0 = blockIdx.x * 128;
    v4f acc[4][4];
    gemm_main(A, W, As, Bs, m0, n0, acc);
    const int lane = threadIdx.x & 63, wid = threadIdx.x >> 6;
    const int wm = wid >> 1, wn = wid & 1, lr = lane & 15, kg = lane >> 4;
    if (blockIdx.z == 0) {
        // fold attention SCALE into qc
        #pragma unroll
        for (int mi = 0; mi < 4; ++mi)
            #pragma unroll
            for (int ni = 0; ni < 4; ++ni)
                #pragma unroll
                for (int r = 0; r < 4; ++r) acc[mi][ni][r] *= 0.125f;
    } else if (blockIdx.z == 3) {
        // fused L2 normalize per 64-col head chunk (wn half == one full head chunk)
        #pragma unroll
        for (int mi = 0; mi < 4; ++mi)
            #pragma unroll
            for (int r = 0; r < 4; ++r) {
                float ss = 0.f;
                #pragma unroll
                for (int ni = 0; ni < 4; ++ni) ss += acc[mi][ni][r] * acc[mi][ni][r];
                ss += __shfl_xor(ss, 1); ss += __shfl_xor(ss, 2);
                ss += __shfl_xor(ss, 4); ss += __shfl_xor(ss, 8);
                float rs = rsqrtf(ss);
                #pragma unroll
                for (int ni = 0; ni < 4; ++ni) acc[mi][ni][r] *= rs;
            }
    }
    #pragma unroll
    for (int mi = 0; mi < 4; ++mi)
        #pragma unroll
        for (int ni = 0; ni < 4; ++ni)
            #pragma unroll
            for (int r = 0; r < 4; ++r) {
                int rowg = m0 + wm * 64 + mi * 16 + kg * 4 + r;
                int colg = n0 + wn * 64 + ni * 16 + lr;
                O[(size_t)rowg * 768 + colg] = f2bf(acc[mi][ni][r]);
            }
}

// final 2 projections + bias -> f32 d_out
__global__ __launch_bounds__(256) void k_gemm_out(
    const u16* __restrict__ ocb, const u16* __restrict__ osb, const u16* __restrict__ Wt,
    const float* __restrict__ bpc, const float* __restrict__ bps, float* __restrict__ out) {
    __shared__ __align__(16) u16 As[8192], Bs[8192];
    const u16* A; const u16* W; const float* bias; float* O;
    if (blockIdx.z == 0) { A = ocb; W = Wt + 5 * 589824; bias = bpc; O = out; }
    else                 { A = osb; W = Wt + 6 * 589824; bias = bps; O = out + 3145728; }
    int m0 = blockIdx.y * 128, n0 = blockIdx.x * 128;
    v4f acc[4][4];
    gemm_main(A, W, As, Bs, m0, n0, acc);
    const int lane = threadIdx.x & 63, wid = threadIdx.x >> 6;
    const int wm = wid >> 1, wn = wid & 1, lr = lane & 15, kg = lane >> 4;
    #pragma unroll
    for (int mi = 0; mi < 4; ++mi)
        #pragma unroll
        for (int ni = 0; ni < 4; ++ni)
            #pragma unroll
            for (int r = 0; r < 4; ++r) {
                int rowg = m0 + wm * 64 + mi * 16 + kg * 4 + r;
                int colg = n0 + wn * 64 + ni * 16 + lr;
                O[(size_t)rowg * 768 + colg] = acc[mi][ni][r] + bias[colg];
            }
}

// ---------------- V transpose: vT[(bh*64+d)*1024 + n] = v[(b*1024+n)*768 + h*64 + d] ----------------
__global__ __launch_bounds__(256) void k_transpose_v(
    const u16* __restrict__ vc, const u16* __restrict__ vs,
    u16* __restrict__ vcT, u16* __restrict__ vsT) {
    __shared__ u16 tile[64][65];
    const u16* src = blockIdx.z ? vs : vc;
    u16* dst = blockIdx.z ? vsT : vcT;
    int bh = blockIdx.y, b = bh / 12, h = bh % 12;
    int n0 = blockIdx.x * 64;
    int t = threadIdx.x;
    #pragma unroll
    for (int i = 0; i < 16; ++i) {
        int idx = i * 256 + t, n = idx >> 6, d = idx & 63;
        tile[n][d] = src[(size_t)(b * 1024 + n0 + n) * 768 + h * 64 + d];
    }
    __syncthreads();
    #pragma unroll
    for (int i = 0; i < 16; ++i) {
        int idx = i * 256 + t, d = idx >> 6, n = idx & 63;
        dst[(size_t)(bh * 64 + d) * 1024 + n0 + n] = tile[n][d];
    }
}

// ---------------- flash attention: S = qc'Kc^T + gamma*Qsn Qsn^T (qc' pre-scaled);
//                  A = softmax(S); oc = A@Vc, os = A@Vs ----------------
// Staging: wave w async-loads its own array (K/Q2/Vc/Vs) via global_load_lds.
__global__ __launch_bounds__(256) void k_attn(
    const u16* __restrict__ qc, const u16* __restrict__ kc, const u16* __restrict__ qsn,
    const u16* __restrict__ vcT, const u16* __restrict__ vsT,
    const float* __restrict__ gamma,
    u16* __restrict__ oc, u16* __restrict__ os) {
    __shared__ __align__(16) u16 K_s[4096], Q2_s[4096], Vc_s[4096], Vs_s[4096], P_s[4096];
    const int t = threadIdx.x, lane = t & 63, w = t >> 6;
    const int lr = lane & 15, kg = lane >> 4;
    const int lrow = lane >> 3, lslot = lane & 7;
    const int sslot = lslot ^ lrow;      // pre-swizzled source slot
    const int qb = blockIdx.x, bh = blockIdx.y, b = bh / 12, h = bh % 12;
    const float gam = gamma[h];
    const float L2E = 1.44269504088896340736f;

    // per-wave staging assignment: wave w owns one array
    const u16* gb; size_t rstride, kstride; char* lds;
    switch (w) {
        case 0:  gb = kc  + (size_t)b * 786432 + h * 64; rstride = 768;  kstride = 768; lds = (char*)K_s;  break;
        case 1:  gb = qsn + (size_t)b * 786432 + h * 64; rstride = 768;  kstride = 768; lds = (char*)Q2_s; break;
        case 2:  gb = vcT + (size_t)bh * 65536;          rstride = 1024; kstride = 1;   lds = (char*)Vc_s; break;
        default: gb = vsT + (size_t)bh * 65536;          rstride = 1024; kstride = 1;   lds = (char*)Vs_s; break;
    }

    // per-wave 16 q-rows: Q fragments in registers for the whole KV sweep
    int qrow = qb * 64 + w * 16 + lr;
    const u16* q1p = qc  + (size_t)(b * 1024 + qrow) * 768 + h * 64 + kg * 8;
    const u16* q2p = qsn + (size_t)(b * 1024 + qrow) * 768 + h * 64 + kg * 8;
    v8bf qcA[2], qsA[2];
    qcA[0] = *reinterpret_cast<const v8bf*>(q1p);
    qcA[1] = *reinterpret_cast<const v8bf*>(q1p + 32);
    qsA[0] = *reinterpret_cast<const v8bf*>(q2p);
    qsA[1] = *reinterpret_cast<const v8bf*>(q2p + 32);

    v4f oAcc[4], sAcc[4];
    #pragma unroll
    for (int i = 0; i < 4; ++i) { oAcc[i] = (v4f){0.f,0.f,0.f,0.f}; sAcc[i] = (v4f){0.f,0.f,0.f,0.f}; }
    float m_i[4] = {-1.0e30f, -1.0e30f, -1.0e30f, -1.0e30f};
    float l_i[4] = {0.f, 0.f, 0.f, 0.f};

    for (int tile = 0; tile < 16; ++tile) {
        int kv0 = tile * 64;
        #pragma unroll
        for (int c = 0; c < 8; ++c) {
            int r = c * 8 + lrow;
            gload16(lds + c * 1024, gb + (size_t)kv0 * kstride + (size_t)r * rstride + sslot * 8);
        }
        __syncthreads();

        // S tile [16 q][64 kv]
        v4f sc[4], ss_[4];
        #pragma unroll
        for (int cb = 0; cb < 4; ++cb) {
            int kr = cb * 16 + lr;
            v4f ac = {0.f,0.f,0.f,0.f}, as = {0.f,0.f,0.f,0.f};
            #pragma unroll
            for (int kk = 0; kk < 2; ++kk) {
                int kb2 = (kk * 32 + kg * 8) * 2;
                int off = kr * 128 + (kb2 ^ ((kr & 7) << 4));
                v8bf kf  = *reinterpret_cast<const v8bf*>(reinterpret_cast<const char*>(K_s) + off);
                v8bf q2f = *reinterpret_cast<const v8bf*>(reinterpret_cast<const char*>(Q2_s) + off);
                ac = __builtin_amdgcn_mfma_f32_16x16x32_bf16(qcA[kk], kf,  ac, 0, 0, 0);
                as = __builtin_amdgcn_mfma_f32_16x16x32_bf16(qsA[kk], q2f, as, 0, 0, 0);
            }
            sc[cb] = ac; ss_[cb] = as;
        }
        // online softmax (rows owned by 16-lane groups; row = kg*4 + r)
        float pv[4][4];
        #pragma unroll
        for (int r = 0; r < 4; ++r) {
            float s0 = fmaf(gam, ss_[0][r], sc[0][r]);
            float s1 = fmaf(gam, ss_[1][r], sc[1][r]);
            float s2 = fmaf(gam, ss_[2][r], sc[2][r]);
            float s3 = fmaf(gam, ss_[3][r], sc[3][r]);
            float mx = fmaxf(fmaxf(s0, s1), fmaxf(s2, s3));
            mx = fmaxf(mx, __shfl_xor(mx, 1));
            mx = fmaxf(mx, __shfl_xor(mx, 2));
            mx = fmaxf(mx, __shfl_xor(mx, 4));
            mx = fmaxf(mx, __shfl_xor(mx, 8));
            float mn = fmaxf(m_i[r], mx);
            float fac = __builtin_exp2f((m_i[r] - mn) * L2E);
            m_i[r] = mn;
            float p0 = __builtin_exp2f((s0 - mn) * L2E);
            float p1 = __builtin_exp2f((s1 - mn) * L2E);
            float p2 = __builtin_exp2f((s2 - mn) * L2E);
            float p3 = __builtin_exp2f((s3 - mn) * L2E);
            pv[0][r] = p0; pv[1][r] = p1; pv[2][r] = p2; pv[3][r] = p3;
            float rs = p0 + p1 + p2 + p3;
            rs += __shfl_xor(rs, 1); rs += __shfl_xor(rs, 2);
            rs += __shfl_xor(rs, 4); rs += __shfl_xor(rs, 8);
            l_i[r] = l_i[r] * fac + rs;
            #pragma unroll
            for (int db = 0; db < 4; ++db) { oAcc[db][r] *= fac; sAcc[db][r] *= fac; }
        }
        // P -> per-wave LDS (C-frag -> A-frag layout transpose)
        #pragma unroll
        for (int cb = 0; cb < 4; ++cb)
            #pragma unroll
            for (int r = 0; r < 4; ++r) {
                int prow = kg * 4 + r, pcol = cb * 16 + lr;
                int off = w * 2048 + prow * 128 + ((pcol * 2) ^ ((prow & 7) << 4));
                *reinterpret_cast<u16*>(reinterpret_cast<char*>(P_s) + off) = f2bf(pv[cb][r]);
            }
        // PV: O[16 q][64 d] += P[16][64] @ V[64][64]
        #pragma unroll
        for (int kk = 0; kk < 2; ++kk) {
            int kb2 = (kk * 32 + kg * 8) * 2;
            int poff = w * 2048 + lr * 128 + (kb2 ^ ((lr & 7) << 4));
            v8bf ap = *reinterpret_cast<const v8bf*>(reinterpret_cast<const char*>(P_s) + poff);
            #pragma unroll
            for (int db = 0; db < 4; ++db) {
                int vr = db * 16 + lr;
                int voff = vr * 128 + (kb2 ^ ((vr & 7) << 4));
                v8bf vcf = *reinterpret_cast<const v8bf*>(reinterpret_cast<const char*>(Vc_s) + voff);
                v8bf vsf = *reinterpret_cast<const v8bf*>(reinterpret_cast<const char*>(Vs_s) + voff);
                oAcc[db] = __builtin_amdgcn_mfma_f32_16x16x32_bf16(ap, vcf, oAcc[db], 0, 0, 0);
                sAcc[db] = __builtin_amdgcn_mfma_f32_16x16x32_bf16(ap, vsf, sAcc[db], 0, 0, 0);
            }
        }
        __syncthreads();
    }
    // epilogue: divide by l, store bf16
    #pragma unroll
    for (int r = 0; r < 4; ++r) {
        float rl = 1.0f / l_i[r];
        int qg = qb * 64 + w * 16 + kg * 4 + r;
        size_t base = (size_t)(b * 1024 + qg) * 768 + h * 64;
        #pragma unroll
        for (int db = 0; db < 4; ++db) {
            oc[base + db * 16 + lr] = f2bf(oAcc[db][r] * rl);
            os[base + db * 16 + lr] = f2bf(sAcc[db][r] * rl);
        }
    }
}

extern "C" void kernel_launch(void* const* d_in, const int* in_sizes, int n_in,
                              void* d_out, int out_size, void* d_ws, size_t ws_size,
                              hipStream_t stream) {
    const float* fc    = (const float*)d_in[0];
    const float* fs    = (const float*)d_in[1];
    const float* Wqc   = (const float*)d_in[2];
    const float* Wqs   = (const float*)d_in[3];
    const float* Wkc   = (const float*)d_in[4];
    const float* Wvc   = (const float*)d_in[5];
    const float* Wvs   = (const float*)d_in[6];
    const float* gamma = (const float*)d_in[7];
    const float* Wpc   = (const float*)d_in[8];
    const float* bpc   = (const float*)d_in[9];
    const float* Wps   = (const float*)d_in[10];
    const float* bps   = (const float*)d_in[11];
    float* out = (float*)d_out;

    const size_t NT = 3145728;  // 4096*768 elements
    u16* ws  = (u16*)d_ws;
    u16* fcb = ws;
    u16* fsb = fcb + NT;
    u16* Wt  = fsb + NT;            // 7 * 589824
    u16* qc  = Wt + (size_t)7 * 589824;
    u16* kc  = qc + NT;
    u16* vc  = kc + NT;
    u16* qs  = vc + NT;
    u16* vs  = qs + NT;
    u16* vcT = vs + NT;
    u16* vsT = vcT + NT;
    u16* ocb = fcb;  // fcb/fsb dead after projections -> reuse for attention outputs
    u16* osb = fsb;

    k_cvt2<<<dim3(3072, 2), 256, 0, stream>>>(fc, fs, fcb, fsb);
    k_transpose_w<<<dim3(24, 24, 7), 256, 0, stream>>>(Wqc, Wkc, Wvc, Wqs, Wvs, Wpc, Wps, Wt);
    k_gemm_proj<<<dim3(6, 32, 5), 256, 0, stream>>>(fcb, fsb, Wt, qc, kc, vc, qs, vs);
    k_transpose_v<<<dim3(16, 48, 2), 256, 0, stream>>>(vc, vs, vcT, vsT);
    k_attn<<<dim3(16, 48), 256, 0, stream>>>(qc, kc, qs, vcT, vsT, gamma, ocb, osb);
    k_gemm_out<<<dim3(6, 32, 2), 256, 0, stream>>>(ocb, osb, Wt, bpc, bps, out);
}